// Round 1
// baseline (307.370 us; speedup 1.0000x reference)
//
#include <hip/hip_runtime.h>
#include <hip/hip_bf16.h>

// Fused map-obs attention (Attention_5815385719367), MI355X/gfx950.
// Structure: prep (projections + GLU + transposes) -> flash-style swapped-QK^T
// MFMA attention with online softmax, O^T orientation, fused epilogue
// (Wo matmul + bias + residual + LayerNorm).
//
// ws layout (needs ~5.9 MB):
//   qbf       [n_map ][64] bf16
//   kbf       [n_obs ][64] bf16
//   vT        [32][n_obs]  bf16   (transposed glu(obs_v))
//   self_score[n_map]      f32
//   gated_map [n_map][32]  f32

typedef float f32x16 __attribute__((ext_vector_type(16)));
typedef float f32x4  __attribute__((ext_vector_type(4)));
typedef short bf16x8 __attribute__((ext_vector_type(8)));
typedef unsigned int u32;

__device__ __forceinline__ u32 cvt_pk_bf16(float lo, float hi) {
    u32 r;
    asm("v_cvt_pk_bf16_f32 %0, %1, %2" : "=v"(r) : "v"(lo), "v"(hi));
    return r;
}
__device__ __forceinline__ void permswap32(u32& a, u32& b) {
    // a.hi_lanes <-> b.lo_lanes  (v_permlane32_swap_b32)
    asm("v_permlane32_swap_b32 %0, %1" : "+v"(a), "+v"(b));
}

// ---------------------------------------------------------------- prep ----
__global__ __launch_bounds__(256) void prep_kernel(
    const float* __restrict__ map_code, const float* __restrict__ obs_code,
    const float* __restrict__ Wq, const float* __restrict__ Wk,
    const float* __restrict__ Wv,
    __hip_bfloat16* __restrict__ qbf, __hip_bfloat16* __restrict__ kbf,
    __hip_bfloat16* __restrict__ vT, float* __restrict__ self_score,
    float* __restrict__ gated_map, int n_map, int n_obs)
{
    __shared__ float xs[4][64];
    const int w = threadIdx.x >> 6;   // wave in block
    const int e = threadIdx.x & 63;   // lane = embed index
    const int r = blockIdx.x * 4 + w; // row (map rows first, then obs rows)
    const int total = n_map + n_obs;
    const bool valid = r < total;
    const bool is_map = r < n_map;
    const float* src = is_map ? (map_code + (size_t)r * 64)
                              : (obs_code + (size_t)(r - n_map) * 64);
    xs[w][e] = valid ? src[e] : 0.0f;
    __syncthreads();
    if (!valid) return;

    float q = 0.f, k = 0.f, v = 0.f;
    #pragma unroll 8
    for (int d = 0; d < 64; ++d) {
        const float xd = xs[w][d];
        q = fmaf(xd, Wq[d * 64 + e], q);
        k = fmaf(xd, Wk[d * 64 + e], k);
        v = fmaf(xd, Wv[d * 64 + e], v);
    }
    // GLU: lanes 0..31 hold a=v[e], need b=v[e+32]
    const float vother = __shfl_xor(v, 32);
    const float sig = 1.0f / (1.0f + exp2f(-vother * 1.44269504089f));
    const float g = v * sig; // valid for lanes e < 32

    if (is_map) {
        qbf[(size_t)r * 64 + e] = __float2bfloat16(q);
        float qk = q * k;
        #pragma unroll
        for (int off = 32; off; off >>= 1) qk += __shfl_xor(qk, off);
        if (e == 0) self_score[r] = qk;
        if (e < 32) gated_map[(size_t)r * 32 + e] = g;
    } else {
        const int j = r - n_map;
        kbf[(size_t)j * 64 + e] = __float2bfloat16(k);
        if (e < 32) vT[(size_t)e * n_obs + j] = __float2bfloat16(g);
    }
}

// ---------------------------------------------------------------- main ----
// 1 wave per block; wave owns 32 q-rows (q = q0 + (lane&31)); KVBLK = 32.
// Swapped QK^T: S^T[key][q] = mfma(A=K[32k x 16d], B=Q^T[16d x 32q]) x4 d-chunks.
//   S^T lane layout: q = lane&31, key = (r&3) + 8*(r>>2) + 4*(lane>>5).
// PV in O^T orientation: O^T[v][q] = mfma(A=vT[32v x 16k], B=P^T[16k x 32q]).
//   -> per-q softmax state (m, lsum) and O rescale are per-lane scalars.
__global__ __launch_bounds__(64) void attn_main(
    const __hip_bfloat16* __restrict__ qbf, const __hip_bfloat16* __restrict__ kbf,
    const __hip_bfloat16* __restrict__ vT, const float* __restrict__ self_score,
    const float* __restrict__ gated_map, const float* __restrict__ map_code,
    const float* __restrict__ Wo, const float* __restrict__ bo,
    const float* __restrict__ gamma, const float* __restrict__ beta,
    float* __restrict__ out, int n_obs)
{
    const int lane = threadIdx.x & 63;
    const int ql = lane & 31;
    const int hi = lane >> 5;
    const int q0 = blockIdx.x * 32;
    const int q = q0 + ql;
    constexpr float IT = 0.18033688011112042f; // 1/(TEMPERATURE * ln2), T=8

    // Q fragments: qf[c][j] = Q[q][16c + 8hi + j]   (B-operand of QK^T mfma)
    bf16x8 qf[4];
    {
        const __hip_bfloat16* qrow = qbf + (size_t)q * 64 + 8 * hi;
        #pragma unroll
        for (int c = 0; c < 4; ++c)
            qf[c] = *reinterpret_cast<const bf16x8*>(qrow + c * 16);
    }

    // online-softmax state; self term is the first "key": p_self = 1
    float m = self_score[q];
    float lsum = 1.0f;

    // O^T accumulator: o[r] = O^T[(r&3)+8*(r>>2)+4hi][q], init = gated_map^T
    f32x16 o;
    {
        const float* gm = gated_map + (size_t)q * 32 + 4 * hi;
        #pragma unroll
        for (int rb = 0; rb < 4; ++rb) {
            const f32x4 t = *reinterpret_cast<const f32x4*>(gm + rb * 8);
            o[rb*4+0] = t[0]; o[rb*4+1] = t[1]; o[rb*4+2] = t[2]; o[rb*4+3] = t[3];
        }
    }

    const __hip_bfloat16* kptr = kbf + (size_t)ql * 64 + 8 * hi;
    const __hip_bfloat16* vptr = vT + (size_t)ql * n_obs + 8 * hi;

    #pragma unroll 2
    for (int key0 = 0; key0 < n_obs; key0 += 32) {
        // ---- QK^T (swapped) ----
        f32x16 s = {};
        const __hip_bfloat16* kb = kptr + (size_t)key0 * 64;
        #pragma unroll
        for (int c = 0; c < 4; ++c) {
            const bf16x8 kf = *reinterpret_cast<const bf16x8*>(kb + c * 16);
            s = __builtin_amdgcn_mfma_f32_32x32x16_bf16(kf, qf[c], s, 0, 0, 0);
        }
        // V fragments (independent of scores — issue early)
        const bf16x8 vf0 = *reinterpret_cast<const bf16x8*>(vptr + key0);
        const bf16x8 vf1 = *reinterpret_cast<const bf16x8*>(vptr + key0 + 16);

        // ---- online softmax (per-lane: one q-row, 16 of 32 keys) ----
        float tmax = s[0];
        #pragma unroll
        for (int r = 1; r < 16; ++r) tmax = fmaxf(tmax, s[r]);
        tmax = fmaxf(tmax, __shfl_xor(tmax, 32)); // combine halves
        const float mnew = fmaxf(m, tmax);
        const float f = exp2f((m - mnew) * IT);
        m = mnew;
        float p[16];
        float tsum = 0.f;
        #pragma unroll
        for (int r = 0; r < 16; ++r) {
            p[r] = exp2f((s[r] - mnew) * IT);
            tsum += p[r];
        }
        tsum += __shfl_xor(tsum, 32);
        lsum = lsum * f + tsum;
        #pragma unroll
        for (int r = 0; r < 16; ++r) o[r] *= f;

        // ---- P -> bf16 PV fragments via cvt_pk + permlane32_swap ----
        // lane holds keys (r&3)+8*(r>>2)+4hi; PV B-frag needs keys 16ks+8hi+j.
        // swap(x0,y0): x0 -> dword0 (keys 8hi+{0,1}), y0 -> dword2 (8hi+{4,5}).
        union { u32 u[4]; bf16x8 v; } pb0, pb1;
        {
            u32 x0 = cvt_pk_bf16(p[0], p[1]);
            u32 x1 = cvt_pk_bf16(p[2], p[3]);
            u32 y0 = cvt_pk_bf16(p[4], p[5]);
            u32 y1 = cvt_pk_bf16(p[6], p[7]);
            permswap32(x0, y0);
            permswap32(x1, y1);
            pb0.u[0] = x0; pb0.u[1] = x1; pb0.u[2] = y0; pb0.u[3] = y1;
        }
        {
            u32 x0 = cvt_pk_bf16(p[8],  p[9]);
            u32 x1 = cvt_pk_bf16(p[10], p[11]);
            u32 y0 = cvt_pk_bf16(p[12], p[13]);
            u32 y1 = cvt_pk_bf16(p[14], p[15]);
            permswap32(x0, y0);
            permswap32(x1, y1);
            pb1.u[0] = x0; pb1.u[1] = x1; pb1.u[2] = y0; pb1.u[3] = y1;
        }
        // ---- PV: O^T += V^T x P^T ----
        o = __builtin_amdgcn_mfma_f32_32x32x16_bf16(vf0, pb0.v, o, 0, 0, 0);
        o = __builtin_amdgcn_mfma_f32_32x32x16_bf16(vf1, pb1.v, o, 0, 0, 0);
    }

    // ---- epilogue: agg = O^T / lsum -> LDS; Wo matmul + residual + LN ----
    __shared__ float aggT[32][33];
    const float inv = 1.0f / lsum;
    #pragma unroll
    for (int r = 0; r < 16; ++r) {
        const int vr = (r & 3) + 8 * (r >> 2) + 4 * hi;
        aggT[vr][ql] = o[r] * inv;
    }
    __syncthreads();

    float wo[32];
    #pragma unroll
    for (int vv = 0; vv < 32; ++vv) wo[vv] = Wo[vv * 64 + lane];
    const float bo_e = bo[lane], ga = gamma[lane], be = beta[lane];

    for (int qq = 0; qq < 32; ++qq) {
        float acc = bo_e + map_code[(size_t)(q0 + qq) * 64 + lane];
        #pragma unroll
        for (int vv = 0; vv < 32; ++vv)
            acc = fmaf(aggT[vv][qq], wo[vv], acc); // LDS broadcast reads
        // LayerNorm over 64 lanes
        float mu = acc;
        #pragma unroll
        for (int off = 32; off; off >>= 1) mu += __shfl_xor(mu, off);
        mu *= (1.0f / 64.0f);
        const float dc = acc - mu;
        float var = dc * dc;
        #pragma unroll
        for (int off = 32; off; off >>= 1) var += __shfl_xor(var, off);
        var *= (1.0f / 64.0f);
        out[(size_t)(q0 + qq) * 64 + lane] =
            dc * rsqrtf(var + 1e-6f) * ga + be;
    }
}

// -------------------------------------------------------------- launch ----
extern "C" void kernel_launch(void* const* d_in, const int* in_sizes, int n_in,
                              void* d_out, int out_size, void* d_ws, size_t ws_size,
                              hipStream_t stream) {
    const float* map_code = (const float*)d_in[0];
    const float* obs_code = (const float*)d_in[1];
    const float* Wq  = (const float*)d_in[2];
    const float* Wk  = (const float*)d_in[3];
    const float* Wv  = (const float*)d_in[4];
    const float* Wo  = (const float*)d_in[5];
    const float* bo  = (const float*)d_in[6];
    const float* gam = (const float*)d_in[7];
    const float* bet = (const float*)d_in[8];
    const int n_map = in_sizes[0] / 64;   // 16384
    const int n_obs = in_sizes[1] / 64;   // 8192

    char* ws = (char*)d_ws;
    __hip_bfloat16* qbf = (__hip_bfloat16*)ws; ws += (size_t)n_map * 64 * 2;
    __hip_bfloat16* kbf = (__hip_bfloat16*)ws; ws += (size_t)n_obs * 64 * 2;
    __hip_bfloat16* vT  = (__hip_bfloat16*)ws; ws += (size_t)32 * n_obs * 2;
    float* self_score   = (float*)ws;          ws += (size_t)n_map * 4;
    float* gated_map    = (float*)ws;          // n_map*32*4

    const int total = n_map + n_obs;
    prep_kernel<<<(total + 3) / 4, 256, 0, stream>>>(
        map_code, obs_code, Wq, Wk, Wv, qbf, kbf, vT, self_score, gated_map,
        n_map, n_obs);
    attn_main<<<n_map / 32, 64, 0, stream>>>(
        qbf, kbf, vT, self_score, gated_map, map_code, Wo, bo, gam, bet,
        (float*)d_out, n_obs);
}

// Round 2
// 136.291 us; speedup vs baseline: 2.2553x; 2.2553x over previous
//
#include <hip/hip_runtime.h>
#include <hip/hip_bf16.h>

// Fused map-obs attention (Attention_5815385719367), MI355X/gfx950.
// R2: KV-split across 8 waves/block (occupancy 5.9% -> ~50%), deterministic
// LDS combine of online-softmax partials, wave-parallel epilogue.
//
// ws layout (~5.9 MB):
//   qbf       [n_map ][64] bf16
//   kbf       [n_obs ][64] bf16
//   vT        [32][n_obs]  bf16   (transposed glu(obs_v))
//   self_score[n_map]      f32
//   gated_map [n_map][32]  f32

typedef float f32x16 __attribute__((ext_vector_type(16)));
typedef short bf16x8 __attribute__((ext_vector_type(8)));
typedef unsigned int u32;

__device__ __forceinline__ u32 cvt_pk_bf16(float lo, float hi) {
    u32 r;
    asm("v_cvt_pk_bf16_f32 %0, %1, %2" : "=v"(r) : "v"(lo), "v"(hi));
    return r;
}
__device__ __forceinline__ void permswap32(u32& a, u32& b) {
    asm("v_permlane32_swap_b32 %0, %1" : "+v"(a), "+v"(b));
}

// ---------------------------------------------------------------- prep ----
__global__ __launch_bounds__(256) void prep_kernel(
    const float* __restrict__ map_code, const float* __restrict__ obs_code,
    const float* __restrict__ Wq, const float* __restrict__ Wk,
    const float* __restrict__ Wv,
    __hip_bfloat16* __restrict__ qbf, __hip_bfloat16* __restrict__ kbf,
    __hip_bfloat16* __restrict__ vT, float* __restrict__ self_score,
    float* __restrict__ gated_map, int n_map, int n_obs)
{
    __shared__ float xs[4][64];
    const int w = threadIdx.x >> 6;   // wave in block
    const int e = threadIdx.x & 63;   // lane = embed index
    const int r = blockIdx.x * 4 + w; // row (map rows first, then obs rows)
    const int total = n_map + n_obs;
    const bool valid = r < total;
    const bool is_map = r < n_map;
    const float* src = is_map ? (map_code + (size_t)r * 64)
                              : (obs_code + (size_t)(r - n_map) * 64);
    xs[w][e] = valid ? src[e] : 0.0f;
    __syncthreads();
    if (!valid) return;

    float q = 0.f, k = 0.f, v = 0.f;
    #pragma unroll 8
    for (int d = 0; d < 64; ++d) {
        const float xd = xs[w][d];
        q = fmaf(xd, Wq[d * 64 + e], q);
        k = fmaf(xd, Wk[d * 64 + e], k);
        v = fmaf(xd, Wv[d * 64 + e], v);
    }
    // GLU: lanes 0..31 hold a=v[e], need b=v[e+32]
    const float vother = __shfl_xor(v, 32);
    const float sig = 1.0f / (1.0f + exp2f(-vother * 1.44269504089f));
    const float g = v * sig; // valid for lanes e < 32

    if (is_map) {
        qbf[(size_t)r * 64 + e] = __float2bfloat16(q);
        float qk = q * k;
        #pragma unroll
        for (int off = 32; off; off >>= 1) qk += __shfl_xor(qk, off);
        if (e == 0) self_score[r] = qk;
        if (e < 32) gated_map[(size_t)r * 32 + e] = g;
    } else {
        const int j = r - n_map;
        kbf[(size_t)j * 64 + e] = __float2bfloat16(k);
        if (e < 32) vT[(size_t)e * n_obs + j] = __float2bfloat16(g);
    }
}

// ---------------------------------------------------------------- main ----
// 8 waves per block; block owns 32 q-rows; wave w handles keys
// [w*n_obs/8, (w+1)*n_obs/8). Swapped QK^T, O^T orientation (see R0/R1).
// Deterministic combine: per-wave (m, l, O^T) -> LDS -> tree merge.
#define WAVES 8
__global__ __launch_bounds__(64 * WAVES) void attn_main(
    const __hip_bfloat16* __restrict__ qbf, const __hip_bfloat16* __restrict__ kbf,
    const __hip_bfloat16* __restrict__ vT, const float* __restrict__ self_score,
    const float* __restrict__ gated_map, const float* __restrict__ map_code,
    const float* __restrict__ Wo, const float* __restrict__ bo,
    const float* __restrict__ gamma, const float* __restrict__ beta,
    float* __restrict__ out, int n_obs)
{
    const int tid  = threadIdx.x;
    const int w    = tid >> 6;
    const int lane = tid & 63;
    const int ql   = lane & 31;
    const int hi   = lane >> 5;
    const int q0   = blockIdx.x * 32;
    const int q    = q0 + ql;
    constexpr float IT = 0.18033688011112042f; // log2(e)/TEMPERATURE, T=8

    __shared__ float oL[WAVES][32][33];
    __shared__ float mL[WAVES][32];
    __shared__ float lL[WAVES][32];
    __shared__ float fwL[WAVES][32];
    __shared__ float invL[32];
    __shared__ float fselfL[32];
    __shared__ float aggT[32][33];

    // Q fragments: qf[c][j] = Q[q][16c + 8hi + j]  (B-operand of QK^T mfma)
    bf16x8 qf[4];
    {
        const __hip_bfloat16* qrow = qbf + (size_t)q * 64 + 8 * hi;
        #pragma unroll
        for (int c = 0; c < 4; ++c)
            qf[c] = *reinterpret_cast<const bf16x8*>(qrow + c * 16);
    }

    // per-wave online-softmax partial state (self term added at combine)
    float m = -3.0e38f;
    float lsum = 0.0f;
    f32x16 o = {};

    const int keys_per_wave = n_obs >> 3;      // 1024
    const int key_begin = w * keys_per_wave;
    const int key_end   = key_begin + keys_per_wave;
    const __hip_bfloat16* kptr = kbf + (size_t)ql * 64 + 8 * hi;
    const __hip_bfloat16* vptr = vT + (size_t)ql * n_obs + 8 * hi;

    #pragma unroll 2
    for (int key0 = key_begin; key0 < key_end; key0 += 32) {
        // ---- QK^T (swapped): S^T[key][q] ----
        f32x16 s = {};
        const __hip_bfloat16* kb = kptr + (size_t)key0 * 64;
        #pragma unroll
        for (int c = 0; c < 4; ++c) {
            const bf16x8 kf = *reinterpret_cast<const bf16x8*>(kb + c * 16);
            s = __builtin_amdgcn_mfma_f32_32x32x16_bf16(kf, qf[c], s, 0, 0, 0);
        }
        const bf16x8 vf0 = *reinterpret_cast<const bf16x8*>(vptr + key0);
        const bf16x8 vf1 = *reinterpret_cast<const bf16x8*>(vptr + key0 + 16);

        // ---- online softmax (lane: one q-row, 16 of 32 keys) ----
        float tmax = s[0];
        #pragma unroll
        for (int r = 1; r < 16; ++r) tmax = fmaxf(tmax, s[r]);
        tmax = fmaxf(tmax, __shfl_xor(tmax, 32));
        const float mnew = fmaxf(m, tmax);
        const float f = exp2f((m - mnew) * IT);
        m = mnew;
        float p[16];
        float tsum = 0.f;
        #pragma unroll
        for (int r = 0; r < 16; ++r) {
            p[r] = exp2f((s[r] - mnew) * IT);
            tsum += p[r];
        }
        tsum += __shfl_xor(tsum, 32);
        lsum = lsum * f + tsum;
        #pragma unroll
        for (int r = 0; r < 16; ++r) o[r] *= f;

        // ---- P -> bf16 PV fragments (cvt_pk + permlane32_swap) ----
        union { u32 u[4]; bf16x8 v; } pb0, pb1;
        {
            u32 x0 = cvt_pk_bf16(p[0], p[1]);
            u32 x1 = cvt_pk_bf16(p[2], p[3]);
            u32 y0 = cvt_pk_bf16(p[4], p[5]);
            u32 y1 = cvt_pk_bf16(p[6], p[7]);
            permswap32(x0, y0);
            permswap32(x1, y1);
            pb0.u[0] = x0; pb0.u[1] = x1; pb0.u[2] = y0; pb0.u[3] = y1;
        }
        {
            u32 x0 = cvt_pk_bf16(p[8],  p[9]);
            u32 x1 = cvt_pk_bf16(p[10], p[11]);
            u32 y0 = cvt_pk_bf16(p[12], p[13]);
            u32 y1 = cvt_pk_bf16(p[14], p[15]);
            permswap32(x0, y0);
            permswap32(x1, y1);
            pb1.u[0] = x0; pb1.u[1] = x1; pb1.u[2] = y0; pb1.u[3] = y1;
        }
        // ---- PV: O^T += V^T x P^T ----
        o = __builtin_amdgcn_mfma_f32_32x32x16_bf16(vf0, pb0.v, o, 0, 0, 0);
        o = __builtin_amdgcn_mfma_f32_32x32x16_bf16(vf1, pb1.v, o, 0, 0, 0);
    }

    // ---- stage partials ----
    if (hi == 0) { mL[w][ql] = m; lL[w][ql] = lsum; }
    #pragma unroll
    for (int r = 0; r < 16; ++r) {
        const int vr = (r & 3) + 8 * (r >> 2) + 4 * hi;
        oL[w][vr][ql] = o[r];
    }
    __syncthreads();

    // ---- combine scalars (wave 0, lanes 0..31): m, fw, lsum, inv ----
    if (w == 0 && hi == 0) {
        const float ms = self_score[q];
        float mf = ms;
        #pragma unroll
        for (int j = 0; j < WAVES; ++j) mf = fmaxf(mf, mL[j][ql]);
        float fs = exp2f((ms - mf) * IT);
        fselfL[ql] = fs;
        float l = fs; // l_self = 1
        #pragma unroll
        for (int j = 0; j < WAVES; ++j) {
            const float fw = exp2f((mL[j][ql] - mf) * IT);
            fwL[j][ql] = fw;
            l = fmaf(fw, lL[j][ql], l);
        }
        invL[ql] = 1.0f / l;
    }
    __syncthreads();

    // ---- combine O^T: 512 threads x 2 (v,q) elements, fixed order ----
    #pragma unroll
    for (int t = tid; t < 1024; t += 64 * WAVES) {
        const int v  = t >> 5;
        const int qq = t & 31;
        float a = fselfL[qq] * gated_map[(size_t)(q0 + qq) * 32 + v];
        #pragma unroll
        for (int j = 0; j < WAVES; ++j)
            a = fmaf(fwL[j][qq], oL[j][v][qq], a);
        aggT[v][qq] = a * invL[qq];
    }
    __syncthreads();

    // ---- epilogue: wave w handles q-rows w*4 .. w*4+3; lane = embed ----
    float wo[32];
    #pragma unroll
    for (int vv = 0; vv < 32; ++vv) wo[vv] = Wo[vv * 64 + lane];
    const float bo_e = bo[lane], ga = gamma[lane], be = beta[lane];

    #pragma unroll
    for (int i = 0; i < 4; ++i) {
        const int qq = w * 4 + i;
        float acc = bo_e + map_code[(size_t)(q0 + qq) * 64 + lane];
        #pragma unroll
        for (int vv = 0; vv < 32; ++vv)
            acc = fmaf(aggT[vv][qq], wo[vv], acc); // LDS broadcast reads
        float mu = acc;
        #pragma unroll
        for (int off = 32; off; off >>= 1) mu += __shfl_xor(mu, off);
        mu *= (1.0f / 64.0f);
        const float dc = acc - mu;
        float var = dc * dc;
        #pragma unroll
        for (int off = 32; off; off >>= 1) var += __shfl_xor(var, off);
        var *= (1.0f / 64.0f);
        out[(size_t)(q0 + qq) * 64 + lane] =
            dc * rsqrtf(var + 1e-6f) * ga + be;
    }
}

// -------------------------------------------------------------- launch ----
extern "C" void kernel_launch(void* const* d_in, const int* in_sizes, int n_in,
                              void* d_out, int out_size, void* d_ws, size_t ws_size,
                              hipStream_t stream) {
    const float* map_code = (const float*)d_in[0];
    const float* obs_code = (const float*)d_in[1];
    const float* Wq  = (const float*)d_in[2];
    const float* Wk  = (const float*)d_in[3];
    const float* Wv  = (const float*)d_in[4];
    const float* Wo  = (const float*)d_in[5];
    const float* bo  = (const float*)d_in[6];
    const float* gam = (const float*)d_in[7];
    const float* bet = (const float*)d_in[8];
    const int n_map = in_sizes[0] / 64;   // 16384
    const int n_obs = in_sizes[1] / 64;   // 8192

    char* ws = (char*)d_ws;
    __hip_bfloat16* qbf = (__hip_bfloat16*)ws; ws += (size_t)n_map * 64 * 2;
    __hip_bfloat16* kbf = (__hip_bfloat16*)ws; ws += (size_t)n_obs * 64 * 2;
    __hip_bfloat16* vT  = (__hip_bfloat16*)ws; ws += (size_t)32 * n_obs * 2;
    float* self_score   = (float*)ws;          ws += (size_t)n_map * 4;
    float* gated_map    = (float*)ws;          // n_map*32*4

    const int total = n_map + n_obs;
    prep_kernel<<<(total + 3) / 4, 256, 0, stream>>>(
        map_code, obs_code, Wq, Wk, Wv, qbf, kbf, vT, self_score, gated_map,
        n_map, n_obs);
    attn_main<<<n_map / 32, 64 * WAVES, 0, stream>>>(
        qbf, kbf, vT, self_score, gated_map, map_code, Wo, bo, gam, bet,
        (float*)d_out, n_obs);
}